// Round 2
// baseline (7640.543 us; speedup 1.0000x reference)
//
#include <hip/hip_runtime.h>
#include <math.h>

#define B_ 512
#define S_ 500
#define SP_ 512
#define DIN_ 14
#define H_ 128
#define N_ 256
#define NT_ 256000      // B_*S_

__device__ __forceinline__ float gelu_f(float x) {
    return 0.5f * x * (1.0f + erff(x * 0.70710678118654752440f));
}

// ---------------- S4 kernel-table precompute (coeffs fused, f64 phase) ---------
__global__ __launch_bounds__(256) void k_kmat(
    const float* __restrict__ logA, const float* __restrict__ Aim,
    const float* __restrict__ Cre, const float* __restrict__ Cim,
    const float* __restrict__ logdt, float* __restrict__ Km)
{
    int lh = blockIdx.x;   // l*H + h, 512 blocks
    __shared__ float  sCr[256], sCi[256], sAr[256];
    __shared__ double sAi[256];
    {
        int n = threadIdx.x;
        int idx = lh * N_ + n;
        double dt  = exp((double)logdt[lh]);
        double Are = -exp((double)logA[idx]);
        double Aiv = (double)Aim[idx];
        double ar  = dt * Are, ai = dt * Aiv;
        double er  = exp(ar);
        double E1r = er * cos(ai) - 1.0, E1i = er * sin(ai);
        double inv = 1.0 / (Are * Are + Aiv * Aiv);
        double qR  = (E1r * Are + E1i * Aiv) * inv;     // (exp(dtA)-1)/A
        double qI  = (E1i * Are - E1r * Aiv) * inv;
        double cre = (double)Cre[idx], cim = (double)Cim[idx];
        sCr[n] = (float)(cre * qR - cim * qI);
        sCi[n] = (float)(cre * qI + cim * qR);
        sAr[n] = (float)ar;
        sAi[n] = ai;
    }
    __syncthreads();
    const double TWO_PI = 6.283185307179586476925286766559;
    const double INV_2PI = 0.15915494309189533576888376337251;
    for (int s = threadIdx.x; s < SP_; s += 256) {
        float acc = 0.0f;
        if (s < S_) {
            float fs = (float)s;
            double fsd = (double)s;
            for (int n = 0; n < N_; ++n) {
                float er = expf(sAr[n] * fs);
                double y = sAi[n] * fsd;
                y -= TWO_PI * rint(y * INV_2PI);
                float sn, cs; sincosf((float)y, &sn, &cs);
                acc += er * (sCr[n] * cs - sCi[n] * sn);
            }
            acc *= 2.0f;
        }
        Km[lh * SP_ + s] = acc;   // zero tail s in [500,512)
    }
}

// ---------------- input projection + positional enc ----------------
__global__ __launch_bounds__(256) void k_inproj(
    const float* __restrict__ x, const float* __restrict__ mask,
    const float* __restrict__ obs, const float* __restrict__ Win,
    const float* __restrict__ bin, float* __restrict__ h)
{
    int tok = blockIdx.x * 2 + (threadIdx.x >> 7);
    int j = threadIdx.x & 127;
    int s = tok % S_;
    float m = mask[tok];
    float acc = bin[j];
#pragma unroll
    for (int d = 0; d < DIN_; ++d) {
        float xc = x[tok * DIN_ + d] * m + obs[tok * DIN_ + d];
        acc += xc * Win[d * H_ + j];
    }
    int jj = j & 63;
    float dv = expf(-0.14391156831212787f * (float)jj);  // ln(1e4)*2/128
    float ang = (float)s * dv;
    float pe = (j < 64) ? sinf(ang) : cosf(ang);
    h[tok * H_ + j] = acc + pe * m;
}

// ---------------- diffusion-time embedding ----------------
__global__ __launch_bounds__(256) void k_temb(
    const int* __restrict__ ts, const float* __restrict__ W1,
    const float* __restrict__ b1, const float* __restrict__ W2,
    const float* __restrict__ b2, float* __restrict__ te)
{
    __shared__ float feat[256];
    __shared__ float mid[256];
    int b = blockIdx.x, j = threadIdx.x;
    float t = (float)ts[b];
    float fr = expf(-0.07252236513367075f * (float)(j & 127)); // ln(1e4)/127
    float ang = t * fr;
    feat[j] = (j < 128) ? sinf(ang) : cosf(ang);
    __syncthreads();
    float acc = b1[j];
    for (int k = 0; k < 256; ++k) acc += feat[k] * W1[k * 256 + j];
    mid[j] = acc / (1.0f + expf(-acc));   // silu
    __syncthreads();
    if (j < 128) {
        float a2 = b2[j];
        for (int k = 0; k < 256; ++k) a2 += mid[k] * W2[k * 128 + j];
        te[b * 128 + j] = a2;
    }
}

// ---------------- LayerNorm + transpose to [CHB,H,SP] (local batch) ---------
__global__ __launch_bounds__(256) void k_ln_t(
    const float* __restrict__ h, const float* __restrict__ g,
    const float* __restrict__ be, float* __restrict__ ut)
{
    int b = blockIdx.x, s0 = blockIdx.y * 64;
    int ntok = min(64, S_ - s0);
    __shared__ float tile[64 * 129];
    __shared__ float mu_[64], rs_[64];
    for (int idx = threadIdx.x; idx < (ntok << 7); idx += 256) {
        int i = idx >> 7, k = idx & 127;
        tile[i * 129 + k] = h[(size_t)(b * S_ + s0 + i) * H_ + k];
    }
    __syncthreads();
    if (threadIdx.x < ntok) {
        int i = threadIdx.x;
        float s1 = 0.f, s2 = 0.f;
        for (int k = 0; k < 128; ++k) { float v = tile[i * 129 + k]; s1 += v; s2 += v * v; }
        float mu = s1 * 0.0078125f;
        float var = s2 * 0.0078125f - mu * mu;
        mu_[i] = mu; rs_[i] = rsqrtf(var + 1e-5f);
    }
    __syncthreads();
    for (int idx = threadIdx.x; idx < 128 * 64; idx += 256) {
        int k = idx >> 6, i = idx & 63;
        if (i < ntok) {
            float v = (tile[i * 129 + k] - mu_[i]) * rs_[i] * g[k] + be[k];
            ut[(size_t)(b * H_ + k) * SP_ + s0 + i] = v;
        }
    }
}

// ---------------- causal Toeplitz conv + D*u + GELU (IN-PLACE on u) ---------
// block: (h, batch-group of 8), 128 threads; thread owns s = 4*tid .. 4*tid+3
__global__ __launch_bounds__(128) void k_conv(
    const float* __restrict__ Km, float* u,
    const float* __restrict__ D)
{
    int hh = blockIdx.x, bg = blockIdx.y;
    __shared__ float Kp[1024];          // 512 zeros then K (K zero-tailed)
    __shared__ float4 u4[8][128];
    int tid = threadIdx.x;
    for (int i = tid; i < 1024; i += 128)
        Kp[i] = (i < 512) ? 0.0f : Km[hh * SP_ + i - 512];
    for (int r = 0; r < 8; ++r) {
        const float4* src = (const float4*)(u + (size_t)((bg * 8 + r) * H_ + hh) * SP_);
        u4[r][tid] = src[tid];
    }
    __syncthreads();
    float acc[8][4];
#pragma unroll
    for (int bb = 0; bb < 8; ++bb)
#pragma unroll
        for (int a = 0; a < 4; ++a) acc[bb][a] = 0.f;
    const float4* K4 = (const float4*)Kp;
    for (int q = 0; q < 125; ++q) {      // t' = 4q + c
        float4 k0 = K4[127 + tid - q];
        float4 k1 = K4[128 + tid - q];
        float w1 = k0.y, w2 = k0.z, w3 = k0.w;
        float w4 = k1.x, w5 = k1.y, w6 = k1.z, w7 = k1.w;
#pragma unroll
        for (int bb = 0; bb < 8; ++bb) {
            float4 uv = u4[bb][q];
            acc[bb][0] += w4 * uv.x; acc[bb][0] += w3 * uv.y; acc[bb][0] += w2 * uv.z; acc[bb][0] += w1 * uv.w;
            acc[bb][1] += w5 * uv.x; acc[bb][1] += w4 * uv.y; acc[bb][1] += w3 * uv.z; acc[bb][1] += w2 * uv.w;
            acc[bb][2] += w6 * uv.x; acc[bb][2] += w5 * uv.y; acc[bb][2] += w4 * uv.z; acc[bb][2] += w3 * uv.w;
            acc[bb][3] += w7 * uv.x; acc[bb][3] += w6 * uv.y; acc[bb][3] += w5 * uv.z; acc[bb][3] += w4 * uv.w;
        }
    }
    if (tid < 125) {                     // s = 4*tid..4*tid+3 < 500
        float Dh = D[hh];
#pragma unroll
        for (int bb = 0; bb < 8; ++bb) {
            float4 uv = u4[bb][tid];
            float4 o;
            o.x = gelu_f(acc[bb][0] + Dh * uv.x);
            o.y = gelu_f(acc[bb][1] + Dh * uv.y);
            o.z = gelu_f(acc[bb][2] + Dh * uv.z);
            o.w = gelu_f(acc[bb][3] + Dh * uv.w);
            ((float4*)(u + (size_t)((bg * 8 + bb) * H_ + hh) * SP_))[tid] = o;
        }
    }
}

// ---------------- S4 output proj: h += yg @ Wo + bo (+te on last) ----------
__global__ __launch_bounds__(256) void k_proj4(
    const float* __restrict__ yt, const float* __restrict__ Wo,
    const float* __restrict__ bo, const float* __restrict__ te,
    float* __restrict__ h)
{
    int b = blockIdx.x, s0 = blockIdx.y * 64;
    int ntok = min(64, S_ - s0);
    __shared__ float At[128 * 68];
    for (int idx = threadIdx.x; idx < 128 * 64; idx += 256) {
        int k = idx >> 6, i = idx & 63;
        if (i < ntok) At[k * 68 + i] = yt[(size_t)(b * H_ + k) * SP_ + s0 + i];
    }
    __syncthreads();
    int ti = threadIdx.x & 15, tj = threadIdx.x >> 4;
    float acc[4][8];
#pragma unroll
    for (int r = 0; r < 4; ++r)
#pragma unroll
        for (int c = 0; c < 8; ++c) acc[r][c] = 0.f;
    for (int k = 0; k < 128; ++k) {
        float4 a4 = *(const float4*)(At + k * 68 + ti * 4);
        float4 w0 = *(const float4*)(Wo + k * 128 + tj * 8);
        float4 w1 = *(const float4*)(Wo + k * 128 + tj * 8 + 4);
        float av[4] = {a4.x, a4.y, a4.z, a4.w};
#pragma unroll
        for (int r = 0; r < 4; ++r) {
            acc[r][0] += av[r] * w0.x; acc[r][1] += av[r] * w0.y;
            acc[r][2] += av[r] * w0.z; acc[r][3] += av[r] * w0.w;
            acc[r][4] += av[r] * w1.x; acc[r][5] += av[r] * w1.y;
            acc[r][6] += av[r] * w1.z; acc[r][7] += av[r] * w1.w;
        }
    }
    float bv[8];
#pragma unroll
    for (int c = 0; c < 8; ++c) bv[c] = bo[tj * 8 + c];
    if (te) {
#pragma unroll
        for (int c = 0; c < 8; ++c) bv[c] += te[b * 128 + tj * 8 + c];
    }
#pragma unroll
    for (int r = 0; r < 4; ++r) {
        int i = ti * 4 + r;
        if (i < ntok) {
            float* hp = h + (size_t)(b * S_ + s0 + i) * H_ + tj * 8;
            float4 h0 = *(float4*)hp, h1 = *(float4*)(hp + 4);
            h0.x += acc[r][0] + bv[0]; h0.y += acc[r][1] + bv[1];
            h0.z += acc[r][2] + bv[2]; h0.w += acc[r][3] + bv[3];
            h1.x += acc[r][4] + bv[4]; h1.y += acc[r][5] + bv[5];
            h1.z += acc[r][6] + bv[6]; h1.w += acc[r][7] + bv[7];
            *(float4*)hp = h0; *(float4*)(hp + 4) = h1;
        }
    }
}

// ---------------- per-token LN stats (mu, rstd) ----------------
__global__ __launch_bounds__(256) void k_lnstat(
    const float* __restrict__ h, float2* __restrict__ st)
{
    int tok = blockIdx.x * 4 + (threadIdx.x >> 6);
    int lane = threadIdx.x & 63;
    const float* hp = h + (size_t)tok * H_;
    float x0 = hp[lane], x1 = hp[lane + 64];
    float s1 = x0 + x1, s2 = x0 * x0 + x1 * x1;
#pragma unroll
    for (int off = 32; off > 0; off >>= 1) {
        s1 += __shfl_xor(s1, off, 64);
        s2 += __shfl_xor(s2, off, 64);
    }
    if (lane == 0) {
        float mu = s1 * 0.0078125f;
        float var = s2 * 0.0078125f - mu * mu;
        st[tok] = make_float2(mu, rsqrtf(var + 1e-5f));
    }
}

// ---------------- residual MLP: LN-fused mm1 (128->256, gelu) --------------
__global__ __launch_bounds__(256) void k_mm1f(
    const float* __restrict__ h, const float2* __restrict__ st,
    const float* __restrict__ g, const float* __restrict__ be,
    const float* __restrict__ W, const float* __restrict__ bias,
    float* __restrict__ out)
{
    int s0 = blockIdx.x * 64;
    __shared__ float At[128 * 68];
    for (int idx = threadIdx.x; idx < 8192; idx += 256) {
        int i = idx >> 7, k = idx & 127;
        float2 ms = st[s0 + i];
        At[k * 68 + i] = (h[(size_t)(s0 + i) * H_ + k] - ms.x) * ms.y * g[k] + be[k];
    }
    __syncthreads();
    int ti = threadIdx.x & 15, tj = threadIdx.x >> 4;
    int j0 = blockIdx.y * 128 + tj * 8;
    float acc[4][8];
#pragma unroll
    for (int r = 0; r < 4; ++r)
#pragma unroll
        for (int c = 0; c < 8; ++c) acc[r][c] = 0.f;
    for (int k = 0; k < 128; ++k) {
        float4 a4 = *(const float4*)(At + k * 68 + ti * 4);
        float4 w0 = *(const float4*)(W + k * 256 + j0);
        float4 w1 = *(const float4*)(W + k * 256 + j0 + 4);
        float av[4] = {a4.x, a4.y, a4.z, a4.w};
#pragma unroll
        for (int r = 0; r < 4; ++r) {
            acc[r][0] += av[r] * w0.x; acc[r][1] += av[r] * w0.y;
            acc[r][2] += av[r] * w0.z; acc[r][3] += av[r] * w0.w;
            acc[r][4] += av[r] * w1.x; acc[r][5] += av[r] * w1.y;
            acc[r][6] += av[r] * w1.z; acc[r][7] += av[r] * w1.w;
        }
    }
    float bv[8];
#pragma unroll
    for (int c = 0; c < 8; ++c) bv[c] = bias[j0 + c];
#pragma unroll
    for (int r = 0; r < 4; ++r) {
        float* op = out + (size_t)(s0 + ti * 4 + r) * 256 + j0;
        float4 o0, o1;
        o0.x = gelu_f(acc[r][0] + bv[0]); o0.y = gelu_f(acc[r][1] + bv[1]);
        o0.z = gelu_f(acc[r][2] + bv[2]); o0.w = gelu_f(acc[r][3] + bv[3]);
        o1.x = gelu_f(acc[r][4] + bv[4]); o1.y = gelu_f(acc[r][5] + bv[5]);
        o1.z = gelu_f(acc[r][6] + bv[6]); o1.w = gelu_f(acc[r][7] + bv[7]);
        *(float4*)op = o0; *(float4*)(op + 4) = o1;
    }
}

// ---------------- residual MLP: mm2 (256->128) + residual ----------------
__global__ __launch_bounds__(256) void k_mm2(
    const float* __restrict__ A, const float* __restrict__ W,
    const float* __restrict__ bias, float* __restrict__ h)
{
    int s0 = blockIdx.x * 64;
    __shared__ float At[128 * 68];
    int ti = threadIdx.x & 15, tj = threadIdx.x >> 4;
    float acc[4][8];
#pragma unroll
    for (int r = 0; r < 4; ++r)
#pragma unroll
        for (int c = 0; c < 8; ++c) acc[r][c] = 0.f;
    for (int kk = 0; kk < 2; ++kk) {
        if (kk) __syncthreads();
        for (int idx = threadIdx.x; idx < 8192; idx += 256) {
            int k = idx & 127, i = idx >> 7;
            At[k * 68 + i] = A[(size_t)(s0 + i) * 256 + kk * 128 + k];
        }
        __syncthreads();
        for (int k = 0; k < 128; ++k) {
            float4 a4 = *(const float4*)(At + k * 68 + ti * 4);
            const float* wr = W + (kk * 128 + k) * 128 + tj * 8;
            float4 w0 = *(const float4*)wr;
            float4 w1 = *(const float4*)(wr + 4);
            float av[4] = {a4.x, a4.y, a4.z, a4.w};
#pragma unroll
            for (int r = 0; r < 4; ++r) {
                acc[r][0] += av[r] * w0.x; acc[r][1] += av[r] * w0.y;
                acc[r][2] += av[r] * w0.z; acc[r][3] += av[r] * w0.w;
                acc[r][4] += av[r] * w1.x; acc[r][5] += av[r] * w1.y;
                acc[r][6] += av[r] * w1.z; acc[r][7] += av[r] * w1.w;
            }
        }
    }
    float bv[8];
#pragma unroll
    for (int c = 0; c < 8; ++c) bv[c] = bias[tj * 8 + c];
#pragma unroll
    for (int r = 0; r < 4; ++r) {
        float* hp = h + (size_t)(s0 + ti * 4 + r) * 128 + tj * 8;
        float4 h0 = *(float4*)hp, h1 = *(float4*)(hp + 4);
        h0.x += acc[r][0] + bv[0]; h0.y += acc[r][1] + bv[1];
        h0.z += acc[r][2] + bv[2]; h0.w += acc[r][3] + bv[3];
        h1.x += acc[r][4] + bv[4]; h1.y += acc[r][5] + bv[5];
        h1.z += acc[r][6] + bv[6]; h1.w += acc[r][7] + bv[7];
        *(float4*)hp = h0; *(float4*)(hp + 4) = h1;
    }
}

// ---------------- output projection 128 -> 14 ----------------
__global__ __launch_bounds__(256) void k_out(
    const float* __restrict__ h, const float* __restrict__ Wout,
    const float* __restrict__ bout, float* __restrict__ out)
{
    int tok0 = blockIdx.x * 16;
    __shared__ float tile[16 * 129];
    for (int idx = threadIdx.x; idx < 2048; idx += 256) {
        int i = idx >> 7, k = idx & 127;
        tile[i * 129 + k] = h[(size_t)(tok0 + i) * H_ + k];
    }
    __syncthreads();
    if (threadIdx.x < 224) {
        int i = threadIdx.x / 14, j = threadIdx.x % 14;
        float acc = bout[j];
        for (int k = 0; k < 128; ++k) acc += tile[i * 129 + k] * Wout[k * 14 + j];
        out[(size_t)(tok0 + i) * 14 + j] = acc;
    }
}

extern "C" void kernel_launch(void* const* d_in, const int* in_sizes, int n_in,
                              void* d_out, int out_size, void* d_ws, size_t ws_size,
                              hipStream_t stream)
{
    (void)in_sizes; (void)n_in; (void)out_size;
    const float* x      = (const float*)d_in[0];
    const int*   tsteps = (const int*)  d_in[1];
    const float* mask   = (const float*)d_in[2];
    const float* obs    = (const float*)d_in[3];
    const float* Win    = (const float*)d_in[4];
    const float* bin    = (const float*)d_in[5];
    const float* tW1    = (const float*)d_in[6];
    const float* tb1    = (const float*)d_in[7];
    const float* tW2    = (const float*)d_in[8];
    const float* tb2    = (const float*)d_in[9];
    const float* lng4   = (const float*)d_in[10];
    const float* lnb4   = (const float*)d_in[11];
    const float* logA   = (const float*)d_in[12];
    const float* Aim    = (const float*)d_in[13];
    const float* Cre    = (const float*)d_in[14];
    const float* Cim    = (const float*)d_in[15];
    const float* Dp     = (const float*)d_in[16];
    const float* logdt  = (const float*)d_in[17];
    const float* Wo     = (const float*)d_in[18];
    const float* bo     = (const float*)d_in[19];
    const float* lng6   = (const float*)d_in[20];
    const float* lnb6   = (const float*)d_in[21];
    const float* rW1    = (const float*)d_in[22];
    const float* rb1    = (const float*)d_in[23];
    const float* rW2    = (const float*)d_in[24];
    const float* rb2    = (const float*)d_in[25];
    const float* Woutp  = (const float*)d_in[26];
    const float* boutp  = (const float*)d_in[27];

    // ---- workspace layout (floats), adaptive to ws_size ----
    float*  ws  = (float*)d_ws;
    float*  h   = ws;                          // 32,768,000
    float*  Km  = h  + 32768000;               //    262,144
    float*  te  = Km + 262144;                 //     65,536
    float2* st  = (float2*)(te + 65536);       //    256,000 float2 = 512,000 f
    float*  big = te + 65536 + 512000;
    size_t  wf  = ws_size / sizeof(float);
    size_t  fixed = 32768000 + 262144 + 65536 + 512000;
    size_t  avail = (wf > fixed) ? (wf - fixed) : 0;

    int CHB = 8;                                // batches per S4 chunk
    for (int c = 512; c >= 8; c >>= 1)
        if ((size_t)c * (H_ * SP_) <= avail) { CHB = c; break; }
    int CHT = 8000;                             // tokens per MLP chunk
    for (int c = 128000; c >= 8000; c >>= 1)
        if ((size_t)c * 256 <= avail) { CHT = c; break; }

    k_kmat<<<512, 256, 0, stream>>>(logA, Aim, Cre, Cim, logdt, Km);
    k_inproj<<<NT_ / 2, 256, 0, stream>>>(x, mask, obs, Win, bin, h);
    k_temb<<<B_, 256, 0, stream>>>(tsteps, tW1, tb1, tW2, tb2, te);

    int nCB = B_ / CHB;
    for (int l = 0; l < 4; ++l) {
        for (int cb = 0; cb < nCB; ++cb) {
            float* hb = h + (size_t)cb * CHB * S_ * H_;
            const float* tep = (l == 3) ? (te + (size_t)cb * CHB * H_) : (const float*)0;
            k_ln_t<<<dim3(CHB, 8), 256, 0, stream>>>(hb, lng4 + l * H_, lnb4 + l * H_, big);
            k_conv<<<dim3(H_, CHB / 8), 128, 0, stream>>>(Km + l * H_ * SP_, big, Dp + l * H_);
            k_proj4<<<dim3(CHB, 8), 256, 0, stream>>>(big, Wo + l * H_ * H_, bo + l * H_,
                                                      tep, hb);
        }
    }

    int nCT = NT_ / CHT;
    for (int l = 0; l < 6; ++l) {
        k_lnstat<<<NT_ / 4, 256, 0, stream>>>(h, st);
        for (int ct = 0; ct < nCT; ++ct) {
            float* hc = h + (size_t)ct * CHT * H_;
            k_mm1f<<<dim3(CHT / 64, 2), 256, 0, stream>>>(
                hc, st + (size_t)ct * CHT, lng6 + l * H_, lnb6 + l * H_,
                rW1 + l * H_ * 256, rb1 + l * 256, big);
            k_mm2<<<dim3(CHT / 64, 1), 256, 0, stream>>>(
                big, rW2 + l * 256 * H_, rb2 + l * H_, hc);
        }
    }
    k_out<<<NT_ / 16, 256, 0, stream>>>(h, Woutp, boutp, (float*)d_out);
}

// Round 3
// 4397.693 us; speedup vs baseline: 1.7374x; 1.7374x over previous
//
#include <hip/hip_runtime.h>
#include <math.h>

#define B_ 512
#define S_ 500
#define SP_ 512
#define DIN_ 14
#define H_ 128
#define N_ 256
#define NT_ 256000      // B_*S_

typedef __attribute__((ext_vector_type(8))) short short8v;   // 8 bf16 (4 VGPR)
typedef __attribute__((ext_vector_type(4))) float f32x4;

__device__ __forceinline__ float gelu_f(float x) {
    return 0.5f * x * (1.0f + erff(x * 0.70710678118654752440f));
}
__device__ __forceinline__ short f2bf(float f) {             // RNE f32->bf16
    unsigned u = __builtin_bit_cast(unsigned, f);
    u += 0x7fffu + ((u >> 16) & 1u);
    return (short)(u >> 16);
}

// ---------------- S4 kernel-table precompute (f64 phase) ----------------
__global__ __launch_bounds__(256) void k_kmat(
    const float* __restrict__ logA, const float* __restrict__ Aim,
    const float* __restrict__ Cre, const float* __restrict__ Cim,
    const float* __restrict__ logdt, float* __restrict__ Km)
{
    int lh = blockIdx.x;   // l*H + h, 512 blocks
    __shared__ float  sCr[256], sCi[256], sAr[256];
    __shared__ double sAi[256];
    {
        int n = threadIdx.x;
        int idx = lh * N_ + n;
        double dt  = exp((double)logdt[lh]);
        double Are = -exp((double)logA[idx]);
        double Aiv = (double)Aim[idx];
        double ar  = dt * Are, ai = dt * Aiv;
        double er  = exp(ar);
        double E1r = er * cos(ai) - 1.0, E1i = er * sin(ai);
        double inv = 1.0 / (Are * Are + Aiv * Aiv);
        double qR  = (E1r * Are + E1i * Aiv) * inv;
        double qI  = (E1i * Are - E1r * Aiv) * inv;
        double cre = (double)Cre[idx], cim = (double)Cim[idx];
        sCr[n] = (float)(cre * qR - cim * qI);
        sCi[n] = (float)(cre * qI + cim * qR);
        sAr[n] = (float)ar;
        sAi[n] = ai;
    }
    __syncthreads();
    const double TWO_PI = 6.283185307179586476925286766559;
    const double INV_2PI = 0.15915494309189533576888376337251;
    for (int s = threadIdx.x; s < SP_; s += 256) {
        float acc = 0.0f;
        if (s < S_) {
            float fs = (float)s;
            double fsd = (double)s;
            for (int n = 0; n < N_; ++n) {
                float er = expf(sAr[n] * fs);
                double y = sAi[n] * fsd;
                y -= TWO_PI * rint(y * INV_2PI);
                float sn, cs; sincosf((float)y, &sn, &cs);
                acc += er * (sCr[n] * cs - sCi[n] * sn);
            }
            acc *= 2.0f;
        }
        Km[lh * SP_ + s] = acc;
    }
}

// ---------------- input projection + positional enc ----------------
__global__ __launch_bounds__(256) void k_inproj(
    const float* __restrict__ x, const float* __restrict__ mask,
    const float* __restrict__ obs, const float* __restrict__ Win,
    const float* __restrict__ bin, float* __restrict__ h)
{
    int tok = blockIdx.x * 2 + (threadIdx.x >> 7);
    int j = threadIdx.x & 127;
    int s = tok % S_;
    float m = mask[tok];
    float acc = bin[j];
#pragma unroll
    for (int d = 0; d < DIN_; ++d) {
        float xc = x[tok * DIN_ + d] * m + obs[tok * DIN_ + d];
        acc += xc * Win[d * H_ + j];
    }
    int jj = j & 63;
    float dv = expf(-0.14391156831212787f * (float)jj);
    float ang = (float)s * dv;
    float pe = (j < 64) ? sinf(ang) : cosf(ang);
    h[(size_t)tok * H_ + j] = acc + pe * m;
}

// ---------------- diffusion-time embedding ----------------
__global__ __launch_bounds__(256) void k_temb(
    const int* __restrict__ ts, const float* __restrict__ W1,
    const float* __restrict__ b1, const float* __restrict__ W2,
    const float* __restrict__ b2, float* __restrict__ te)
{
    __shared__ float feat[256];
    __shared__ float mid[256];
    int b = blockIdx.x, j = threadIdx.x;
    float t = (float)ts[b];
    float fr = expf(-0.07252236513367075f * (float)(j & 127));
    float ang = t * fr;
    feat[j] = (j < 128) ? sinf(ang) : cosf(ang);
    __syncthreads();
    float acc = b1[j];
    for (int k = 0; k < 256; ++k) acc += feat[k] * W1[k * 256 + j];
    mid[j] = acc / (1.0f + expf(-acc));
    __syncthreads();
    if (j < 128) {
        float a2 = b2[j];
        for (int k = 0; k < 256; ++k) a2 += mid[k] * W2[k * 128 + j];
        te[b * 128 + j] = a2;
    }
}

// ---------------- weight transpose + bf16 cast (once per call) -------------
__global__ __launch_bounds__(256) void k_wcast(
    const float* __restrict__ Wo, const float* __restrict__ rW1,
    const float* __restrict__ rW2,
    short* __restrict__ WoT, short* __restrict__ W1T, short* __restrict__ W2T)
{
    int i = blockIdx.x * 256 + threadIdx.x;
    if (i < 65536) {                        // WoT: 4 x [n=128][k=128]
        int l = i >> 14, r = i & 16383, n = r >> 7, k = r & 127;
        WoT[i] = f2bf(Wo[(size_t)(l * 128 + k) * 128 + n]);
    } else if (i < 262144) {                // W1T: 6 x [n=256][k=128]
        int j = i - 65536;
        int l = j >> 15, r = j & 32767, n = r >> 7, k = r & 127;
        W1T[j] = f2bf(rW1[(size_t)(l * 128 + k) * 256 + n]);
    } else if (i < 458752) {                // W2T: 6 x [n=128][k=256]
        int j = i - 262144;
        int l = j >> 15, r = j & 32767, n = r >> 8, k = r & 255;
        W2T[j] = f2bf(rW2[(size_t)(l * 256 + k) * 128 + n]);
    }
}

// ---------------- LayerNorm + transpose to [CHB,H,SP] ----------------
__global__ __launch_bounds__(256) void k_ln_t(
    const float* __restrict__ h, const float* __restrict__ g,
    const float* __restrict__ be, float* __restrict__ ut)
{
    int b = blockIdx.x, s0 = blockIdx.y * 64;
    int ntok = min(64, S_ - s0);
    __shared__ float tile[64 * 129];
    __shared__ float mu_[64], rs_[64];
    for (int idx = threadIdx.x; idx < (ntok << 7); idx += 256) {
        int i = idx >> 7, k = idx & 127;
        tile[i * 129 + k] = h[(size_t)(b * S_ + s0 + i) * H_ + k];
    }
    __syncthreads();
    if (threadIdx.x < ntok) {
        int i = threadIdx.x;
        float s1 = 0.f, s2 = 0.f;
        for (int k = 0; k < 128; ++k) { float v = tile[i * 129 + k]; s1 += v; s2 += v * v; }
        float mu = s1 * 0.0078125f;
        float var = s2 * 0.0078125f - mu * mu;
        mu_[i] = mu; rs_[i] = rsqrtf(var + 1e-5f);
    }
    __syncthreads();
    for (int idx = threadIdx.x; idx < 128 * 64; idx += 256) {
        int k = idx >> 6, i = idx & 63;
        if (i < ntok) {
            float v = (tile[i * 129 + k] - mu_[i]) * rs_[i] * g[k] + be[k];
            ut[(size_t)(b * H_ + k) * SP_ + s0 + i] = v;
        }
    }
}

// ---------------- causal Toeplitz conv + D*u + GELU (in-place, f32) --------
__global__ __launch_bounds__(128) void k_conv(
    const float* __restrict__ Km, float* u, const float* __restrict__ D)
{
    int hh = blockIdx.x, bg = blockIdx.y;
    __shared__ float Kp[1024];
    __shared__ float4 u4[8][128];
    int tid = threadIdx.x;
    for (int i = tid; i < 1024; i += 128)
        Kp[i] = (i < 512) ? 0.0f : Km[hh * SP_ + i - 512];
    for (int r = 0; r < 8; ++r) {
        const float4* src = (const float4*)(u + (size_t)((bg * 8 + r) * H_ + hh) * SP_);
        u4[r][tid] = src[tid];
    }
    __syncthreads();
    float acc[8][4];
#pragma unroll
    for (int bb = 0; bb < 8; ++bb)
#pragma unroll
        for (int a = 0; a < 4; ++a) acc[bb][a] = 0.f;
    const float4* K4 = (const float4*)Kp;
    for (int q = 0; q < 125; ++q) {
        float4 k0 = K4[127 + tid - q];
        float4 k1 = K4[128 + tid - q];
        float w1 = k0.y, w2 = k0.z, w3 = k0.w;
        float w4 = k1.x, w5 = k1.y, w6 = k1.z, w7 = k1.w;
#pragma unroll
        for (int bb = 0; bb < 8; ++bb) {
            float4 uv = u4[bb][q];
            acc[bb][0] += w4 * uv.x; acc[bb][0] += w3 * uv.y; acc[bb][0] += w2 * uv.z; acc[bb][0] += w1 * uv.w;
            acc[bb][1] += w5 * uv.x; acc[bb][1] += w4 * uv.y; acc[bb][1] += w3 * uv.z; acc[bb][1] += w2 * uv.w;
            acc[bb][2] += w6 * uv.x; acc[bb][2] += w5 * uv.y; acc[bb][2] += w4 * uv.z; acc[bb][2] += w3 * uv.w;
            acc[bb][3] += w7 * uv.x; acc[bb][3] += w6 * uv.y; acc[bb][3] += w5 * uv.z; acc[bb][3] += w4 * uv.w;
        }
    }
    if (tid < 125) {
        float Dh = D[hh];
#pragma unroll
        for (int bb = 0; bb < 8; ++bb) {
            float4 uv = u4[bb][tid];
            float4 o;
            o.x = gelu_f(acc[bb][0] + Dh * uv.x);
            o.y = gelu_f(acc[bb][1] + Dh * uv.y);
            o.z = gelu_f(acc[bb][2] + Dh * uv.z);
            o.w = gelu_f(acc[bb][3] + Dh * uv.w);
            ((float4*)(u + (size_t)((bg * 8 + bb) * H_ + hh) * SP_))[tid] = o;
        }
    }
}

// ---------------- transpose + bf16 cast: ut[CHB,H,SP] -> yb[CHB*512,H] -----
__global__ __launch_bounds__(256) void k_tcast(
    const float* __restrict__ yt, short* __restrict__ yb)
{
    int b = blockIdx.x, s0 = blockIdx.y * 64;
    __shared__ float tile[128][65];
    for (int idx = threadIdx.x; idx < 8192; idx += 256) {
        int hh = idx >> 6, sc = idx & 63;
        tile[hh][sc] = yt[((size_t)b * 128 + hh) * SP_ + s0 + sc];
    }
    __syncthreads();
    for (int idx = threadIdx.x; idx < 8192; idx += 256) {
        int sc = idx >> 7, hh = idx & 127;
        int s = s0 + sc;
        float v = (s < S_) ? tile[hh][sc] : 0.f;
        yb[((size_t)b * 512 + s) * 128 + hh] = f2bf(v);
    }
}

// ---------------- LN + bf16 cast for residual MLP input ----------------
__global__ __launch_bounds__(256) void k_lnz(
    const float* __restrict__ h, const float* __restrict__ g,
    const float* __restrict__ be, short* __restrict__ zb)
{
    int tok = blockIdx.x * 4 + (threadIdx.x >> 6);
    int lane = threadIdx.x & 63;
    const float* hp = h + (size_t)tok * H_;
    float2 x = *(const float2*)(hp + lane * 2);
    float s1 = x.x + x.y, s2 = x.x * x.x + x.y * x.y;
#pragma unroll
    for (int off = 32; off > 0; off >>= 1) {
        s1 += __shfl_xor(s1, off, 64);
        s2 += __shfl_xor(s2, off, 64);
    }
    float mu = s1 * 0.0078125f;
    float var = s2 * 0.0078125f - mu * mu;
    float rs = rsqrtf(var + 1e-5f);
    unsigned lo = (unsigned short)f2bf((x.x - mu) * rs * g[lane * 2]     + be[lane * 2]);
    unsigned hi = (unsigned short)f2bf((x.y - mu) * rs * g[lane * 2 + 1] + be[lane * 2 + 1]);
    *((unsigned*)(zb + (size_t)tok * H_) + lane) = lo | (hi << 16);
}

// ---------------- bf16 MFMA GEMM, 128x128 tile, 4 waves ----------------
// A [M][KTOT] bf16 row-major, BT [Ntot][KTOT] bf16 (B transposed).
// EPI 0: out=bf16 gelu(acc+bias), stride 256 (mm1)
// EPI 1: hres[r*128+c] += acc+bias (mm2)
// EPI 2: proj4: rows padded b*512+s, s<500 -> hres[(b*500+s)*128+c] += acc+bias(+te)
template<int KTOT, int EPI>
__global__ __launch_bounds__(256) void k_gemm(
    const short* __restrict__ A, const short* __restrict__ BT,
    const float* __restrict__ bias, const float* __restrict__ te,
    short* __restrict__ outb, float* __restrict__ hres)
{
    __shared__ short As[16384];   // [128 rows][128 k] swizzled, 32KB
    __shared__ short Bs[16384];
    int tid = threadIdx.x;
    int bm = blockIdx.x, gy = blockIdx.y;
    const short* Ab = A + (size_t)bm * 128 * KTOT;
    const short* Bb = BT + (size_t)gy * 128 * KTOT;

    f32x4 acc[4][4];
    f32x4 zv = {0.f, 0.f, 0.f, 0.f};
#pragma unroll
    for (int m = 0; m < 4; ++m)
#pragma unroll
        for (int n = 0; n < 4; ++n) acc[m][n] = zv;

    int lane = tid & 63, wid = tid >> 6;
    int wm = wid >> 1, wn = wid & 1;
    int fr = lane & 15, ko = (lane >> 4) << 3;

    for (int k0 = 0; k0 < KTOT; k0 += 128) {
        if (k0) __syncthreads();
#pragma unroll
        for (int p = 0; p < 8; ++p) {
            int idx = p * 256 + tid;
            int row = idx >> 4, c16 = idx & 15;
            int byt = (row * 256 + c16 * 16) ^ ((row & 7) << 4);
            *(short8v*)((char*)As + byt) =
                *(const short8v*)(Ab + (size_t)row * KTOT + k0 + c16 * 8);
            *(short8v*)((char*)Bs + byt) =
                *(const short8v*)(Bb + (size_t)row * KTOT + k0 + c16 * 8);
        }
        __syncthreads();
#pragma unroll
        for (int ks = 0; ks < 4; ++ks) {
            short8v a[4], b[4];
#pragma unroll
            for (int m = 0; m < 4; ++m) {
                int row = wm * 64 + m * 16 + fr;
                int byt = (row * 256 + (ks * 32 + ko) * 2) ^ ((row & 7) << 4);
                a[m] = *(const short8v*)((const char*)As + byt);
            }
#pragma unroll
            for (int n = 0; n < 4; ++n) {
                int row = wn * 64 + n * 16 + fr;
                int byt = (row * 256 + (ks * 32 + ko) * 2) ^ ((row & 7) << 4);
                b[n] = *(const short8v*)((const char*)Bs + byt);
            }
#pragma unroll
            for (int m = 0; m < 4; ++m)
#pragma unroll
                for (int n = 0; n < 4; ++n)
                    acc[m][n] = __builtin_amdgcn_mfma_f32_16x16x32_bf16(
                        a[m], b[n], acc[m][n], 0, 0, 0);
        }
    }

#pragma unroll
    for (int m = 0; m < 4; ++m) {
        int R0 = bm * 128 + wm * 64 + m * 16 + (lane >> 4) * 4;
#pragma unroll
        for (int n = 0; n < 4; ++n) {
            int C = wn * 64 + n * 16 + fr;
            if (EPI == 0) {
                int Cg = gy * 128 + C;
                float bj = bias[Cg];
#pragma unroll
                for (int j = 0; j < 4; ++j)
                    outb[(size_t)(R0 + j) * 256 + Cg] = f2bf(gelu_f(acc[m][n][j] + bj));
            } else if (EPI == 1) {
                float bj = bias[C];
#pragma unroll
                for (int j = 0; j < 4; ++j)
                    hres[(size_t)(R0 + j) * 128 + C] += acc[m][n][j] + bj;
            } else {
                float bj = bias[C];
#pragma unroll
                for (int j = 0; j < 4; ++j) {
                    int R = R0 + j;
                    int b_ = R >> 9, s = R & 511;
                    if (s < S_) {
                        float t = te ? te[b_ * 128 + C] : 0.f;
                        hres[((size_t)b_ * S_ + s) * 128 + C] += acc[m][n][j] + bj + t;
                    }
                }
            }
        }
    }
}

// ---------------- output projection 128 -> 14 (f32) ----------------
__global__ __launch_bounds__(256) void k_out(
    const float* __restrict__ h, const float* __restrict__ Wout,
    const float* __restrict__ bout, float* __restrict__ out)
{
    int tok0 = blockIdx.x * 16;
    __shared__ float tile[16 * 129];
    for (int idx = threadIdx.x; idx < 2048; idx += 256) {
        int i = idx >> 7, k = idx & 127;
        tile[i * 129 + k] = h[(size_t)(tok0 + i) * H_ + k];
    }
    __syncthreads();
    if (threadIdx.x < 224) {
        int i = threadIdx.x / 14, j = threadIdx.x % 14;
        float acc = bout[j];
        for (int k = 0; k < 128; ++k) acc += tile[i * 129 + k] * Wout[k * 14 + j];
        out[(size_t)(tok0 + i) * 14 + j] = acc;
    }
}

extern "C" void kernel_launch(void* const* d_in, const int* in_sizes, int n_in,
                              void* d_out, int out_size, void* d_ws, size_t ws_size,
                              hipStream_t stream)
{
    (void)in_sizes; (void)n_in; (void)out_size;
    const float* x      = (const float*)d_in[0];
    const int*   tsteps = (const int*)  d_in[1];
    const float* mask   = (const float*)d_in[2];
    const float* obs    = (const float*)d_in[3];
    const float* Win    = (const float*)d_in[4];
    const float* bin    = (const float*)d_in[5];
    const float* tW1    = (const float*)d_in[6];
    const float* tb1    = (const float*)d_in[7];
    const float* tW2    = (const float*)d_in[8];
    const float* tb2    = (const float*)d_in[9];
    const float* lng4   = (const float*)d_in[10];
    const float* lnb4   = (const float*)d_in[11];
    const float* logA   = (const float*)d_in[12];
    const float* Aim    = (const float*)d_in[13];
    const float* Cre    = (const float*)d_in[14];
    const float* Cim    = (const float*)d_in[15];
    const float* Dp     = (const float*)d_in[16];
    const float* logdt  = (const float*)d_in[17];
    const float* Wo     = (const float*)d_in[18];
    const float* bo     = (const float*)d_in[19];
    const float* lng6   = (const float*)d_in[20];
    const float* lnb6   = (const float*)d_in[21];
    const float* rW1    = (const float*)d_in[22];
    const float* rb1    = (const float*)d_in[23];
    const float* rW2    = (const float*)d_in[24];
    const float* rb2    = (const float*)d_in[25];
    const float* Woutp  = (const float*)d_in[26];
    const float* boutp  = (const float*)d_in[27];

    // ---- workspace layout (floats), adaptive to ws_size ----
    float* ws  = (float*)d_ws;
    float* h   = ws;                             // 32,768,000 f
    float* Km  = h + 32768000;                   //    262,144 f
    float* te  = Km + 262144;                    //     65,536 f
    short* WoT = (short*)(te + 65536);           //     65,536 bf16
    short* W1T = WoT + 65536;                    //    196,608 bf16
    short* W2T = W1T + 196608;                   //    196,608 bf16
    float* big = (float*)(W2T + 196608);
    size_t wf  = ws_size / sizeof(float);
    size_t fixed = 32768000 + 262144 + 65536 + 229376;
    size_t avail = (wf > fixed) ? (wf - fixed) : 0;

    int CHB = 8;   // batches per S4 chunk: needs CHB*98304 floats
    for (int c = 512; c >= 8; c >>= 1)
        if ((size_t)c * 98304 <= avail) { CHB = c; break; }
    int CHT = 16000; // tokens per MLP chunk: needs CHT*192 floats
    {
        const int cand[5] = {256000, 128000, 64000, 32000, 16000};
        for (int i = 0; i < 5; ++i)
            if ((size_t)cand[i] * 192 <= avail) { CHT = cand[i]; break; }
    }

    k_kmat<<<512, 256, 0, stream>>>(logA, Aim, Cre, Cim, logdt, Km);
    k_inproj<<<NT_ / 2, 256, 0, stream>>>(x, mask, obs, Win, bin, h);
    k_temb<<<B_, 256, 0, stream>>>(tsteps, tW1, tb1, tW2, tb2, te);
    k_wcast<<<1792, 256, 0, stream>>>(Wo, rW1, rW2, WoT, W1T, W2T);

    // ---- S4 layers ----
    int nCB = B_ / CHB;
    for (int l = 0; l < 4; ++l) {
        for (int cb = 0; cb < nCB; ++cb) {
            float* hb = h + (size_t)cb * CHB * S_ * H_;
            float* ut = big;
            short* yb = (short*)(big + (size_t)CHB * 65536);
            const float* tep = (l == 3) ? (te + (size_t)cb * CHB * H_) : (const float*)0;
            k_ln_t<<<dim3(CHB, 8), 256, 0, stream>>>(hb, lng4 + l * H_, lnb4 + l * H_, ut);
            k_conv<<<dim3(H_, CHB / 8), 128, 0, stream>>>(Km + l * H_ * SP_, ut, Dp + l * H_);
            k_tcast<<<dim3(CHB, 8), 256, 0, stream>>>(ut, yb);
            k_gemm<128, 2><<<dim3(CHB * 4, 1), 256, 0, stream>>>(
                yb, WoT + l * 16384, bo + l * H_, tep, (short*)0, hb);
        }
    }

    // ---- residual MLP layers ----
    int nCT = NT_ / CHT;
    for (int l = 0; l < 6; ++l) {
        for (int ct = 0; ct < nCT; ++ct) {
            float* hc = h + (size_t)ct * CHT * H_;
            short* zb = (short*)big;
            short* midb = zb + (size_t)CHT * 128;
            k_lnz<<<CHT / 4, 256, 0, stream>>>(hc, lng6 + l * H_, lnb6 + l * H_, zb);
            k_gemm<128, 0><<<dim3(CHT / 128, 2), 256, 0, stream>>>(
                zb, W1T + l * 32768, rb1 + l * 256, (const float*)0, midb, (float*)0);
            k_gemm<256, 1><<<dim3(CHT / 128, 1), 256, 0, stream>>>(
                midb, W2T + l * 32768, rb2 + l * H_, (const float*)0, (short*)0, hc);
        }
    }
    k_out<<<NT_ / 16, 256, 0, stream>>>(h, Woutp, boutp, (float*)d_out);
}

// Round 4
// 2934.360 us; speedup vs baseline: 2.6038x; 1.4987x over previous
//
#include <hip/hip_runtime.h>
#include <math.h>

#define B_ 512
#define S_ 500
#define SP_ 512
#define DIN_ 14
#define H_ 128
#define N_ 256
#define NT_ 256000      // B_*S_

typedef __attribute__((ext_vector_type(8))) short short8v;   // 8 bf16 (4 VGPR)
typedef __attribute__((ext_vector_type(4))) float f32x4;

__device__ __forceinline__ float gelu_f(float x) {
    return 0.5f * x * (1.0f + erff(x * 0.70710678118654752440f));
}
__device__ __forceinline__ short f2bf(float f) {             // RNE f32->bf16
    unsigned u = __builtin_bit_cast(unsigned, f);
    u += 0x7fffu + ((u >> 16) & 1u);
    return (short)(u >> 16);
}
__device__ __forceinline__ float bf2f(short s) {
    return __builtin_bit_cast(float, ((unsigned)(unsigned short)s) << 16);
}

// ---------------- S4 kernel-table precompute (f64 phase) ----------------
__global__ __launch_bounds__(256) void k_kmat(
    const float* __restrict__ logA, const float* __restrict__ Aim,
    const float* __restrict__ Cre, const float* __restrict__ Cim,
    const float* __restrict__ logdt, float* __restrict__ Km)
{
    int lh = blockIdx.x;   // l*H + h, 512 blocks
    __shared__ float  sCr[256], sCi[256], sAr[256];
    __shared__ double sAi[256];
    {
        int n = threadIdx.x;
        int idx = lh * N_ + n;
        double dt  = exp((double)logdt[lh]);
        double Are = -exp((double)logA[idx]);
        double Aiv = (double)Aim[idx];
        double ar  = dt * Are, ai = dt * Aiv;
        double er  = exp(ar);
        double E1r = er * cos(ai) - 1.0, E1i = er * sin(ai);
        double inv = 1.0 / (Are * Are + Aiv * Aiv);
        double qR  = (E1r * Are + E1i * Aiv) * inv;
        double qI  = (E1i * Are - E1r * Aiv) * inv;
        double cre = (double)Cre[idx], cim = (double)Cim[idx];
        sCr[n] = (float)(cre * qR - cim * qI);
        sCi[n] = (float)(cre * qI + cim * qR);
        sAr[n] = (float)ar;
        sAi[n] = ai;
    }
    __syncthreads();
    const double TWO_PI = 6.283185307179586476925286766559;
    const double INV_2PI = 0.15915494309189533576888376337251;
    for (int s = threadIdx.x; s < SP_; s += 256) {
        float acc = 0.0f;
        if (s < S_) {
            float fs = (float)s;
            double fsd = (double)s;
            for (int n = 0; n < N_; ++n) {
                float er = expf(sAr[n] * fs);
                double y = sAi[n] * fsd;
                y -= TWO_PI * rint(y * INV_2PI);
                float sn, cs; sincosf((float)y, &sn, &cs);
                acc += er * (sCr[n] * cs - sCi[n] * sn);
            }
            acc *= 2.0f;
        }
        Km[lh * SP_ + s] = acc;
    }
}

// ---------------- Toeplitz block build: Km row -> 4 x [128][128] bf16 ------
__global__ __launch_bounds__(256) void k_toep(
    const float* __restrict__ Kl, short* __restrict__ Tblk)
{
    int hh = blockIdx.x, d = blockIdx.y;
    const float* Kr = Kl + hh * SP_;
    short* Tb = Tblk + (((size_t)hh * 4 + d) << 14);
    int base = d * 128;
    for (int i = threadIdx.x; i < 16384; i += 256) {
        int s = i >> 7, t = i & 127;
        int diff = base + s - t;
        float v = (diff >= 0 && diff < S_) ? Kr[diff] : 0.f;
        Tb[i] = f2bf(v);
    }
}

// ---------------- input projection + positional enc ----------------
__global__ __launch_bounds__(256) void k_inproj(
    const float* __restrict__ x, const float* __restrict__ mask,
    const float* __restrict__ obs, const float* __restrict__ Win,
    const float* __restrict__ bin, float* __restrict__ h)
{
    int tok = blockIdx.x * 2 + (threadIdx.x >> 7);
    int j = threadIdx.x & 127;
    int s = tok % S_;
    float m = mask[tok];
    float acc = bin[j];
#pragma unroll
    for (int d = 0; d < DIN_; ++d) {
        float xc = x[tok * DIN_ + d] * m + obs[tok * DIN_ + d];
        acc += xc * Win[d * H_ + j];
    }
    int jj = j & 63;
    float dv = expf(-0.14391156831212787f * (float)jj);
    float ang = (float)s * dv;
    float pe = (j < 64) ? sinf(ang) : cosf(ang);
    h[(size_t)tok * H_ + j] = acc + pe * m;
}

// ---------------- diffusion-time embedding ----------------
__global__ __launch_bounds__(256) void k_temb(
    const int* __restrict__ ts, const float* __restrict__ W1,
    const float* __restrict__ b1, const float* __restrict__ W2,
    const float* __restrict__ b2, float* __restrict__ te)
{
    __shared__ float feat[256];
    __shared__ float mid[256];
    int b = blockIdx.x, j = threadIdx.x;
    float t = (float)ts[b];
    float fr = expf(-0.07252236513367075f * (float)(j & 127));
    float ang = t * fr;
    feat[j] = (j < 128) ? sinf(ang) : cosf(ang);
    __syncthreads();
    float acc = b1[j];
    for (int k = 0; k < 256; ++k) acc += feat[k] * W1[k * 256 + j];
    mid[j] = acc / (1.0f + expf(-acc));
    __syncthreads();
    if (j < 128) {
        float a2 = b2[j];
        for (int k = 0; k < 256; ++k) a2 += mid[k] * W2[k * 128 + j];
        te[b * 128 + j] = a2;
    }
}

// ---------------- weight transpose + bf16 cast (once per call) -------------
__global__ __launch_bounds__(256) void k_wcast(
    const float* __restrict__ Wo, const float* __restrict__ rW1,
    const float* __restrict__ rW2,
    short* __restrict__ WoT, short* __restrict__ W1T, short* __restrict__ W2T)
{
    int i = blockIdx.x * 256 + threadIdx.x;
    if (i < 65536) {                        // WoT: 4 x [n=128][k=128]
        int l = i >> 14, r = i & 16383, n = r >> 7, k = r & 127;
        WoT[i] = f2bf(Wo[(size_t)(l * 128 + k) * 128 + n]);
    } else if (i < 262144) {                // W1T: 6 x [n=256][k=128]
        int j = i - 65536;
        int l = j >> 15, r = j & 32767, n = r >> 7, k = r & 127;
        W1T[j] = f2bf(rW1[(size_t)(l * 128 + k) * 256 + n]);
    } else if (i < 458752) {                // W2T: 6 x [n=128][k=256]
        int j = i - 262144;
        int l = j >> 15, r = j & 32767, n = r >> 8, k = r & 255;
        W2T[j] = f2bf(rW2[(size_t)(l * 256 + k) * 128 + n]);
    }
}

// ---------------- LayerNorm + transpose -> bf16 ubt[B][H][SP], zero tail ---
__global__ __launch_bounds__(256) void k_ln_tb(
    const float* __restrict__ h, const float* __restrict__ g,
    const float* __restrict__ be, short* __restrict__ ubt)
{
    int b = blockIdx.x, s0 = blockIdx.y * 64;
    int ntok = min(64, S_ - s0);
    __shared__ float tile[64 * 129];
    __shared__ float mu_[64], rs_[64];
    for (int idx = threadIdx.x; idx < (ntok << 7); idx += 256) {
        int i = idx >> 7, k = idx & 127;
        tile[i * 129 + k] = h[(size_t)(b * S_ + s0 + i) * H_ + k];
    }
    __syncthreads();
    if (threadIdx.x < ntok) {
        int i = threadIdx.x;
        float s1 = 0.f, s2 = 0.f;
        for (int k = 0; k < 128; ++k) { float v = tile[i * 129 + k]; s1 += v; s2 += v * v; }
        float mu = s1 * 0.0078125f;
        float var = s2 * 0.0078125f - mu * mu;
        mu_[i] = mu; rs_[i] = rsqrtf(var + 1e-5f);
    }
    __syncthreads();
    // write pairs (2 bf16 per dword); zero-fill s >= S_
    for (int idx = threadIdx.x; idx < 128 * 32; idx += 256) {
        int k = idx >> 5, i = (idx & 31) * 2;
        float v0 = (i < ntok)     ? (tile[i * 129 + k]       - mu_[i])     * rs_[i]     * g[k] + be[k] : 0.f;
        float v1 = (i + 1 < ntok) ? (tile[(i + 1) * 129 + k] - mu_[i + 1]) * rs_[i + 1] * g[k] + be[k] : 0.f;
        unsigned lo = (unsigned short)f2bf(v0);
        unsigned hi = (unsigned short)f2bf(v1);
        *(unsigned*)(ubt + ((size_t)b * H_ + k) * SP_ + s0 + i) = lo | (hi << 16);
    }
}

// ---------------- MFMA Toeplitz conv: Y = U * T, + D*u, GELU --------------
// grid (h=128, si=4, CHB/128); ubt/ybt [CHB][H][SP] bf16
__global__ __launch_bounds__(256) void k_cgemm(
    const short* __restrict__ ubt, const short* __restrict__ Tblk,
    const float* __restrict__ D, short* __restrict__ ybt)
{
    __shared__ short As[16384];
    __shared__ short Bs[16384];
    int hh = blockIdx.x, si = blockIdx.y, bt = blockIdx.z;
    int tid = threadIdx.x;
    int lane = tid & 63, wid = tid >> 6;
    int wm = wid >> 1, wn = wid & 1;
    int fr = lane & 15, ko = (lane >> 4) << 3;
    const short* Ab = ubt + ((size_t)(bt * 128) * H_ + hh) * SP_;  // row stride H_*SP_

    f32x4 acc[4][4];
    f32x4 zv = {0.f, 0.f, 0.f, 0.f};
#pragma unroll
    for (int m = 0; m < 4; ++m)
#pragma unroll
        for (int n = 0; n < 4; ++n) acc[m][n] = zv;

    for (int tj = 0; tj <= si; ++tj) {
        if (tj) __syncthreads();
        const short* Bb = Tblk + (((size_t)hh * 4 + (si - tj)) << 14);
#pragma unroll
        for (int p = 0; p < 8; ++p) {
            int idx = p * 256 + tid;
            int row = idx >> 4, c16 = idx & 15;
            int byt = (row * 256 + c16 * 16) ^ ((row & 7) << 4);
            *(short8v*)((char*)As + byt) =
                *(const short8v*)(Ab + (size_t)row * (H_ * SP_) + tj * 128 + c16 * 8);
            *(short8v*)((char*)Bs + byt) =
                *(const short8v*)(Bb + row * 128 + c16 * 8);
        }
        __syncthreads();
#pragma unroll
        for (int ks = 0; ks < 4; ++ks) {
            short8v a[4], b[4];
#pragma unroll
            for (int m = 0; m < 4; ++m) {
                int row = wm * 64 + m * 16 + fr;
                int byt = (row * 256 + (ks * 32 + ko) * 2) ^ ((row & 7) << 4);
                a[m] = *(const short8v*)((const char*)As + byt);
            }
#pragma unroll
            for (int n = 0; n < 4; ++n) {
                int row = wn * 64 + n * 16 + fr;
                int byt = (row * 256 + (ks * 32 + ko) * 2) ^ ((row & 7) << 4);
                b[n] = *(const short8v*)((const char*)Bs + byt);
            }
#pragma unroll
            for (int m = 0; m < 4; ++m)
#pragma unroll
                for (int n = 0; n < 4; ++n)
                    acc[m][n] = __builtin_amdgcn_mfma_f32_16x16x32_bf16(
                        a[m], b[n], acc[m][n], 0, 0, 0);
        }
        if (tj < si) __syncthreads();
    }

    float Dh = D[hh];
#pragma unroll
    for (int m = 0; m < 4; ++m) {
        int b0 = wm * 64 + m * 16 + (lane >> 4) * 4;
#pragma unroll
        for (int n = 0; n < 4; ++n) {
            int sC = si * 128 + wn * 64 + n * 16 + fr;
#pragma unroll
            for (int j = 0; j < 4; ++j) {
                int bg = bt * 128 + b0 + j;
                size_t off = ((size_t)bg * H_ + hh) * SP_ + sC;
                float u = bf2f(ubt[off]);
                ybt[off] = f2bf(gelu_f(acc[m][n][j] + Dh * u));
            }
        }
    }
}

// ---------------- transpose bf16: ybt[B][H][SP] -> yb[B*512][H] ------------
__global__ __launch_bounds__(256) void k_tcastb(
    const short* __restrict__ ybt, short* __restrict__ yb)
{
    int b = blockIdx.x, s0 = blockIdx.y * 64;
    __shared__ short tile[128][66];
    for (int idx = threadIdx.x; idx < 8192; idx += 256) {
        int hh = idx >> 6, sc = idx & 63;
        tile[hh][sc] = ybt[((size_t)b * H_ + hh) * SP_ + s0 + sc];
    }
    __syncthreads();
    for (int idx = threadIdx.x; idx < 8192; idx += 256) {
        int sc = idx >> 7, hh = idx & 127;
        yb[((size_t)b * 512 + s0 + sc) * 128 + hh] = tile[hh][sc];
    }
}

// ---------------- LN + bf16 cast for residual MLP input ----------------
__global__ __launch_bounds__(256) void k_lnz(
    const float* __restrict__ h, const float* __restrict__ g,
    const float* __restrict__ be, short* __restrict__ zb)
{
    int tok = blockIdx.x * 4 + (threadIdx.x >> 6);
    int lane = threadIdx.x & 63;
    const float* hp = h + (size_t)tok * H_;
    float2 x = *(const float2*)(hp + lane * 2);
    float s1 = x.x + x.y, s2 = x.x * x.x + x.y * x.y;
#pragma unroll
    for (int off = 32; off > 0; off >>= 1) {
        s1 += __shfl_xor(s1, off, 64);
        s2 += __shfl_xor(s2, off, 64);
    }
    float mu = s1 * 0.0078125f;
    float var = s2 * 0.0078125f - mu * mu;
    float rs = rsqrtf(var + 1e-5f);
    unsigned lo = (unsigned short)f2bf((x.x - mu) * rs * g[lane * 2]     + be[lane * 2]);
    unsigned hi = (unsigned short)f2bf((x.y - mu) * rs * g[lane * 2 + 1] + be[lane * 2 + 1]);
    *((unsigned*)(zb + (size_t)tok * H_) + lane) = lo | (hi << 16);
}

// ---------------- bf16 MFMA GEMM, 128x128 tile, 4 waves ----------------
// EPI 0: out=bf16 gelu(acc+bias), stride 256 (mm1)
// EPI 1: hres[r*128+c] += acc+bias (mm2)
// EPI 2: proj4: rows b*512+s, s<500 -> hres[(b*500+s)*128+c] += acc+bias(+te)
template<int KTOT, int EPI>
__global__ __launch_bounds__(256) void k_gemm(
    const short* __restrict__ A, const short* __restrict__ BT,
    const float* __restrict__ bias, const float* __restrict__ te,
    short* __restrict__ outb, float* __restrict__ hres)
{
    __shared__ short As[16384];
    __shared__ short Bs[16384];
    int tid = threadIdx.x;
    int bm = blockIdx.x, gy = blockIdx.y;
    const short* Ab = A + (size_t)bm * 128 * KTOT;
    const short* Bb = BT + (size_t)gy * 128 * KTOT;

    f32x4 acc[4][4];
    f32x4 zv = {0.f, 0.f, 0.f, 0.f};
#pragma unroll
    for (int m = 0; m < 4; ++m)
#pragma unroll
        for (int n = 0; n < 4; ++n) acc[m][n] = zv;

    int lane = tid & 63, wid = tid >> 6;
    int wm = wid >> 1, wn = wid & 1;
    int fr = lane & 15, ko = (lane >> 4) << 3;

    for (int k0 = 0; k0 < KTOT; k0 += 128) {
        if (k0) __syncthreads();
#pragma unroll
        for (int p = 0; p < 8; ++p) {
            int idx = p * 256 + tid;
            int row = idx >> 4, c16 = idx & 15;
            int byt = (row * 256 + c16 * 16) ^ ((row & 7) << 4);
            *(short8v*)((char*)As + byt) =
                *(const short8v*)(Ab + (size_t)row * KTOT + k0 + c16 * 8);
            *(short8v*)((char*)Bs + byt) =
                *(const short8v*)(Bb + (size_t)row * KTOT + k0 + c16 * 8);
        }
        __syncthreads();
#pragma unroll
        for (int ks = 0; ks < 4; ++ks) {
            short8v a[4], b[4];
#pragma unroll
            for (int m = 0; m < 4; ++m) {
                int row = wm * 64 + m * 16 + fr;
                int byt = (row * 256 + (ks * 32 + ko) * 2) ^ ((row & 7) << 4);
                a[m] = *(const short8v*)((const char*)As + byt);
            }
#pragma unroll
            for (int n = 0; n < 4; ++n) {
                int row = wn * 64 + n * 16 + fr;
                int byt = (row * 256 + (ks * 32 + ko) * 2) ^ ((row & 7) << 4);
                b[n] = *(const short8v*)((const char*)Bs + byt);
            }
#pragma unroll
            for (int m = 0; m < 4; ++m)
#pragma unroll
                for (int n = 0; n < 4; ++n)
                    acc[m][n] = __builtin_amdgcn_mfma_f32_16x16x32_bf16(
                        a[m], b[n], acc[m][n], 0, 0, 0);
        }
    }

#pragma unroll
    for (int m = 0; m < 4; ++m) {
        int R0 = bm * 128 + wm * 64 + m * 16 + (lane >> 4) * 4;
#pragma unroll
        for (int n = 0; n < 4; ++n) {
            int C = wn * 64 + n * 16 + fr;
            if (EPI == 0) {
                int Cg = gy * 128 + C;
                float bj = bias[Cg];
#pragma unroll
                for (int j = 0; j < 4; ++j)
                    outb[(size_t)(R0 + j) * 256 + Cg] = f2bf(gelu_f(acc[m][n][j] + bj));
            } else if (EPI == 1) {
                float bj = bias[C];
#pragma unroll
                for (int j = 0; j < 4; ++j)
                    hres[(size_t)(R0 + j) * 128 + C] += acc[m][n][j] + bj;
            } else {
                float bj = bias[C];
#pragma unroll
                for (int j = 0; j < 4; ++j) {
                    int R = R0 + j;
                    int b_ = R >> 9, s = R & 511;
                    if (s < S_) {
                        float t = te ? te[b_ * 128 + C] : 0.f;
                        hres[((size_t)b_ * S_ + s) * 128 + C] += acc[m][n][j] + bj + t;
                    }
                }
            }
        }
    }
}

// ---------------- output projection 128 -> 14 (f32) ----------------
__global__ __launch_bounds__(256) void k_out(
    const float* __restrict__ h, const float* __restrict__ Wout,
    const float* __restrict__ bout, float* __restrict__ out)
{
    int tok0 = blockIdx.x * 16;
    __shared__ float tile[16 * 129];
    for (int idx = threadIdx.x; idx < 2048; idx += 256) {
        int i = idx >> 7, k = idx & 127;
        tile[i * 129 + k] = h[(size_t)(tok0 + i) * H_ + k];
    }
    __syncthreads();
    if (threadIdx.x < 224) {
        int i = threadIdx.x / 14, j = threadIdx.x % 14;
        float acc = bout[j];
        for (int k = 0; k < 128; ++k) acc += tile[i * 129 + k] * Wout[k * 14 + j];
        out[(size_t)(tok0 + i) * 14 + j] = acc;
    }
}

extern "C" void kernel_launch(void* const* d_in, const int* in_sizes, int n_in,
                              void* d_out, int out_size, void* d_ws, size_t ws_size,
                              hipStream_t stream)
{
    (void)in_sizes; (void)n_in; (void)out_size;
    const float* x      = (const float*)d_in[0];
    const int*   tsteps = (const int*)  d_in[1];
    const float* mask   = (const float*)d_in[2];
    const float* obs    = (const float*)d_in[3];
    const float* Win    = (const float*)d_in[4];
    const float* bin    = (const float*)d_in[5];
    const float* tW1    = (const float*)d_in[6];
    const float* tb1    = (const float*)d_in[7];
    const float* tW2    = (const float*)d_in[8];
    const float* tb2    = (const float*)d_in[9];
    const float* lng4   = (const float*)d_in[10];
    const float* lnb4   = (const float*)d_in[11];
    const float* logA   = (const float*)d_in[12];
    const float* Aim    = (const float*)d_in[13];
    const float* Cre    = (const float*)d_in[14];
    const float* Cim    = (const float*)d_in[15];
    const float* Dp     = (const float*)d_in[16];
    const float* logdt  = (const float*)d_in[17];
    const float* Wo     = (const float*)d_in[18];
    const float* bo     = (const float*)d_in[19];
    const float* lng6   = (const float*)d_in[20];
    const float* lnb6   = (const float*)d_in[21];
    const float* rW1    = (const float*)d_in[22];
    const float* rb1    = (const float*)d_in[23];
    const float* rW2    = (const float*)d_in[24];
    const float* rb2    = (const float*)d_in[25];
    const float* Woutp  = (const float*)d_in[26];
    const float* boutp  = (const float*)d_in[27];

    // ---- workspace layout (floats), adaptive to ws_size ----
    float* ws  = (float*)d_ws;
    float* h   = ws;                             // 32,768,000 f
    float* Km  = h + 32768000;                   //    262,144 f
    float* te  = Km + 262144;                    //     65,536 f
    short* WoT = (short*)(te + 65536);           //     65,536 bf16
    short* W1T = WoT + 65536;                    //    196,608 bf16
    short* W2T = W1T + 196608;                   //    196,608 bf16
    float* big = (float*)(W2T + 196608);
    size_t wf  = ws_size / sizeof(float);
    size_t fixed = 32768000 + 262144 + 65536 + 229376;
    size_t avail = (wf > fixed) ? (wf - fixed) : 0;   // floats in big region

    // S4 chunk: needs CHB*65536 + 4,194,304 floats (ubt+ybt bf16, Tblk bf16)
    int CHB = 128;
    for (int c = 512; c >= 128; c >>= 1)
        if ((size_t)c * 65536 + 4194304 <= avail) { CHB = c; break; }
    // MLP chunk: needs CHT*192 floats (zb + midb bf16)
    int CHT = 16000;
    {
        const int cand[5] = {256000, 128000, 64000, 32000, 16000};
        for (int i = 0; i < 5; ++i)
            if ((size_t)cand[i] * 192 <= avail) { CHT = cand[i]; break; }
    }

    short* ubt  = (short*)big;                   // CHB*65536 bf16 (also yb alias)
    short* ybt  = ubt + (size_t)CHB * 65536;     // CHB*65536 bf16
    short* Tblk = ybt + (size_t)CHB * 65536;     // 8,388,608 bf16
    short* yb   = ubt;                           // alias (ubt dead after k_cgemm)

    k_kmat<<<512, 256, 0, stream>>>(logA, Aim, Cre, Cim, logdt, Km);
    k_inproj<<<NT_ / 2, 256, 0, stream>>>(x, mask, obs, Win, bin, h);
    k_temb<<<B_, 256, 0, stream>>>(tsteps, tW1, tb1, tW2, tb2, te);
    k_wcast<<<1792, 256, 0, stream>>>(Wo, rW1, rW2, WoT, W1T, W2T);

    // ---- S4 layers ----
    int nCB = B_ / CHB;
    for (int l = 0; l < 4; ++l) {
        k_toep<<<dim3(H_, 4), 256, 0, stream>>>(Km + (size_t)l * H_ * SP_, Tblk);
        for (int cb = 0; cb < nCB; ++cb) {
            float* hb = h + (size_t)cb * CHB * S_ * H_;
            const float* tep = (l == 3) ? (te + (size_t)cb * CHB * H_) : (const float*)0;
            k_ln_tb<<<dim3(CHB, 8), 256, 0, stream>>>(hb, lng4 + l * H_, lnb4 + l * H_, ubt);
            k_cgemm<<<dim3(H_, 4, CHB / 128), 256, 0, stream>>>(ubt, Tblk, Dp + l * H_, ybt);
            k_tcastb<<<dim3(CHB, 8), 256, 0, stream>>>(ybt, yb);
            k_gemm<128, 2><<<dim3(CHB * 4, 1), 256, 0, stream>>>(
                yb, WoT + l * 16384, bo + l * H_, tep, (short*)0, hb);
        }
    }

    // ---- residual MLP layers ----
    int nCT = NT_ / CHT;
    for (int l = 0; l < 6; ++l) {
        for (int ct = 0; ct < nCT; ++ct) {
            float* hc = h + (size_t)ct * CHT * H_;
            short* zb = (short*)big;
            short* midb = zb + (size_t)CHT * 128;
            k_lnz<<<CHT / 4, 256, 0, stream>>>(hc, lng6 + l * H_, lnb6 + l * H_, zb);
            k_gemm<128, 0><<<dim3(CHT / 128, 2), 256, 0, stream>>>(
                zb, W1T + l * 32768, rb1 + l * 256, (const float*)0, midb, (float*)0);
            k_gemm<256, 1><<<dim3(CHT / 128, 1), 256, 0, stream>>>(
                midb, W2T + l * 32768, rb2 + l * H_, (const float*)0, (short*)0, hc);
        }
    }
    k_out<<<NT_ / 16, 256, 0, stream>>>(h, Woutp, boutp, (float*)d_out);
}